// Round 1
// baseline (419.601 us; speedup 1.0000x reference)
//
#include <hip/hip_runtime.h>
#include <stdint.h>
#include <stddef.h>

#define IN_F    4096
#define OUT_F   4096
#define MTOK    8192      // 4 * 2048 tokens
#define RANK    16
#define SCALING 2.0f      // alpha/rank = 32/16

typedef __attribute__((ext_vector_type(8))) short          bf16x8;
typedef __attribute__((ext_vector_type(4))) float          f32x4;
typedef __attribute__((ext_vector_type(4))) float          fl4;
typedef __attribute__((ext_vector_type(4))) unsigned short u16x4;
typedef __attribute__((ext_vector_type(8))) unsigned short u16x8;

static __device__ __forceinline__ unsigned short f2bf(float f) {
  union { float f; uint32_t u; } v; v.f = f;
  return (unsigned short)((v.u + 0x7fffu + ((v.u >> 16) & 1u)) >> 16);  // RNE
}

static __device__ __forceinline__ void gload16(const void* g, void* l) {
  __builtin_amdgcn_global_load_lds(
      (const __attribute__((address_space(1))) uint32_t*)g,
      (__attribute__((address_space(3))) uint32_t*)l,
      16, 0, 0);
}

// ---------------------------------------------------------------------------
// W_eff[o][i] = bf16( W[o][i] + SCALING * sum_r B[o][r] * A[r][i] )
// one block per output row o; 256 threads x 4 cols x 4 iters = 4096 cols
// ---------------------------------------------------------------------------
__global__ void merge_w_kernel(const float* __restrict__ W,
                               const float* __restrict__ lA,
                               const float* __restrict__ lB,
                               unsigned short* __restrict__ Weff) {
  __shared__ float Bs[RANK];
  const int o = blockIdx.x;
  if (threadIdx.x < RANK) Bs[threadIdx.x] = lB[o * RANK + threadIdx.x] * SCALING;
  __syncthreads();
  for (int c = threadIdx.x * 4; c < IN_F; c += 256 * 4) {
    fl4 w = *(const fl4*)(W + (size_t)o * IN_F + c);
#pragma unroll
    for (int r = 0; r < RANK; ++r) {
      const float b = Bs[r];
      const fl4 a = *(const fl4*)(lA + (size_t)r * IN_F + c);
      w[0] += b * a[0]; w[1] += b * a[1]; w[2] += b * a[2]; w[3] += b * a[3];
    }
    u16x4 p;
    p[0] = f2bf(w[0]); p[1] = f2bf(w[1]); p[2] = f2bf(w[2]); p[3] = f2bf(w[3]);
    *(u16x4*)(Weff + (size_t)o * IN_F + c) = p;
  }
}

// ---------------------------------------------------------------------------
// x f32 -> bf16, 8 elems per thread
// ---------------------------------------------------------------------------
__global__ void conv_x_kernel(const float* __restrict__ x,
                              unsigned short* __restrict__ xb) {
  const size_t i = ((size_t)blockIdx.x * 256 + threadIdx.x) * 8;
  const fl4 a = *(const fl4*)(x + i);
  const fl4 b = *(const fl4*)(x + i + 4);
  u16x8 p;
  p[0] = f2bf(a[0]); p[1] = f2bf(a[1]); p[2] = f2bf(a[2]); p[3] = f2bf(a[3]);
  p[4] = f2bf(b[0]); p[5] = f2bf(b[1]); p[6] = f2bf(b[2]); p[7] = f2bf(b[3]);
  *(u16x8*)(xb + i) = p;
}

// ---------------------------------------------------------------------------
// GEMM: Out[m][n] = sum_k X[m][k] * Weff[n][k]   (both operands K-contiguous)
// m97 structure: 128x128 tile, BK=32, 4 waves (2x2), 4x4 16x16x32 frags/wave
// XBF16: A-source is bf16 in ws (global_load_lds); else f32 with reg-staging
// ---------------------------------------------------------------------------
template <bool XBF16>
__global__ __launch_bounds__(256) void gemm_kernel(
    const void* __restrict__ Xsrc,
    const unsigned short* __restrict__ Weff,
    float* __restrict__ Out) {
  __shared__ unsigned short As[128][32];
  __shared__ unsigned short Bs[128][32];

  const int tid  = threadIdx.x;
  const int lane = tid & 63;
  const int wave = tid >> 6;
  const int wr = wave >> 1;           // wave row (2)
  const int wc = wave & 1;            // wave col (2)
  const int fr = lane & 15;
  const int fq = lane >> 4;

  const int bid = blockIdx.x;
  const int tm = bid & 63;            // 64 M-tiles
  const int tn = bid >> 6;            // 32 N-tiles
  const int m0 = tm * 128;
  const int n0 = tn * 128;

  f32x4 acc[4][4];
#pragma unroll
  for (int i = 0; i < 4; ++i)
#pragma unroll
    for (int j = 0; j < 4; ++j) acc[i][j] = (f32x4){0.f, 0.f, 0.f, 0.f};

  const int srow = tid >> 2;          // 0..63
  const int sseg = tid & 3;           // 0..3 (8 bf16 each)

  for (int k0 = 0; k0 < IN_F; k0 += 32) {
    if (k0) __syncthreads();          // all waves done reading previous tiles

    // ---- stage B (Weff tile) via global_load_lds, 2 issues of 64 rows ----
    {
      const unsigned short* gB = Weff + (size_t)(n0 + srow) * IN_F + k0 + sseg * 8;
      gload16(gB, &Bs[srow][sseg * 8]);
      gload16(gB + (size_t)64 * IN_F, &Bs[64 + srow][sseg * 8]);
    }
    // ---- stage A (x tile) ----
    if (XBF16) {
      const unsigned short* X = (const unsigned short*)Xsrc;
      const unsigned short* gA = X + (size_t)(m0 + srow) * IN_F + k0 + sseg * 8;
      gload16(gA, &As[srow][sseg * 8]);
      gload16(gA + (size_t)64 * IN_F, &As[64 + srow][sseg * 8]);
    } else {
      const float* X = (const float*)Xsrc;
#pragma unroll
      for (int it = 0; it < 4; ++it) {
        const int c   = tid + it * 256;   // 0..1023 chunks of 4 elems
        const int row = c >> 3;
        const int c4  = (c & 7) * 4;
        const fl4 v = *(const fl4*)(X + (size_t)(m0 + row) * IN_F + k0 + c4);
        u16x4 p;
        p[0] = f2bf(v[0]); p[1] = f2bf(v[1]); p[2] = f2bf(v[2]); p[3] = f2bf(v[3]);
        *(u16x4*)&As[row][c4] = p;
      }
    }
    __syncthreads();                  // drains vmcnt/lgkmcnt + barrier

    bf16x8 af[4], bfm[4];
#pragma unroll
    for (int m = 0; m < 4; ++m)
      af[m] = *(const bf16x8*)&As[wr * 64 + m * 16 + fr][fq * 8];
#pragma unroll
    for (int n = 0; n < 4; ++n)
      bfm[n] = *(const bf16x8*)&Bs[wc * 64 + n * 16 + fr][fq * 8];
#pragma unroll
    for (int m = 0; m < 4; ++m)
#pragma unroll
      for (int n = 0; n < 4; ++n)
        acc[m][n] = __builtin_amdgcn_mfma_f32_16x16x32_bf16(af[m], bfm[n], acc[m][n], 0, 0, 0);
  }

  // ---- epilogue: C[row=m*16+fq*4+j][col=n*16+fr] (HW-verified mapping) ----
#pragma unroll
  for (int m = 0; m < 4; ++m) {
    const int row0 = m0 + wr * 64 + m * 16 + fq * 4;
#pragma unroll
    for (int n = 0; n < 4; ++n) {
      const int col = n0 + wc * 64 + n * 16 + fr;
#pragma unroll
      for (int j = 0; j < 4; ++j)
        Out[(size_t)(row0 + j) * OUT_F + col] = acc[m][n][j];
    }
  }
}

// ---------------------------------------------------------------------------
// never-path fallbacks (tiny ws): correct but slow
// ---------------------------------------------------------------------------
__global__ void lora_r_kernel(const float* __restrict__ x,
                              const float* __restrict__ lA,
                              float* __restrict__ r) {
  const int idx = blockIdx.x * 256 + threadIdx.x;   // MTOK*RANK threads
  const int m = idx / RANK, rr = idx % RANK;
  float acc = 0.f;
  for (int k = 0; k < IN_F; ++k)
    acc += x[(size_t)m * IN_F + k] * lA[(size_t)rr * IN_F + k];
  r[idx] = acc * SCALING;
}

__global__ void naive_out_kernel(const float* __restrict__ x,
                                 const float* __restrict__ W,
                                 const float* __restrict__ lB,
                                 const float* __restrict__ r,
                                 float* __restrict__ out) {
  const size_t idx = (size_t)blockIdx.x * 256 + threadIdx.x;
  const int m = (int)(idx / OUT_F), n = (int)(idx % OUT_F);
  float acc = 0.f;
  for (int k = 0; k < IN_F; ++k)
    acc += x[(size_t)m * IN_F + k] * W[(size_t)n * IN_F + k];
#pragma unroll
  for (int rr = 0; rr < RANK; ++rr)
    acc += r[(size_t)m * RANK + rr] * lB[(size_t)n * RANK + rr];
  out[idx] = acc;
}

// ---------------------------------------------------------------------------
extern "C" void kernel_launch(void* const* d_in, const int* in_sizes, int n_in,
                              void* d_out, int out_size, void* d_ws, size_t ws_size,
                              hipStream_t stream) {
  const float* x  = (const float*)d_in[0];
  const float* W  = (const float*)d_in[1];
  const float* lA = (const float*)d_in[2];
  const float* lB = (const float*)d_in[3];
  float* out = (float*)d_out;

  const size_t weff_bytes = (size_t)OUT_F * IN_F * 2;   // 32 MiB
  const size_t xb_bytes   = (size_t)MTOK * IN_F * 2;    // 64 MiB
  const int nblk_gemm = (MTOK / 128) * (OUT_F / 128);   // 2048

  if (ws_size >= weff_bytes) {
    unsigned short* Weff = (unsigned short*)d_ws;
    merge_w_kernel<<<OUT_F, 256, 0, stream>>>(W, lA, lB, Weff);
    if (ws_size >= weff_bytes + xb_bytes) {
      unsigned short* xb = (unsigned short*)((char*)d_ws + weff_bytes);
      conv_x_kernel<<<(MTOK * (size_t)IN_F) / (256 * 8), 256, 0, stream>>>(x, xb);
      gemm_kernel<true><<<nblk_gemm, 256, 0, stream>>>(xb, Weff, out);
    } else {
      gemm_kernel<false><<<nblk_gemm, 256, 0, stream>>>(x, Weff, out);
    }
  } else {
    // last-resort correctness path: needs 512 KiB
    float* r = (float*)d_ws;
    lora_r_kernel<<<(MTOK * RANK) / 256, 256, 0, stream>>>(x, lA, r);
    naive_out_kernel<<<(size_t)MTOK * OUT_F / 256, 256, 0, stream>>>(x, W, lB, r, out);
  }
}

// Round 2
// 363.953 us; speedup vs baseline: 1.1529x; 1.1529x over previous
//
#include <hip/hip_runtime.h>
#include <stdint.h>
#include <stddef.h>

#define IN_F    4096
#define OUT_F   4096
#define MTOK    8192      // 4 * 2048 tokens
#define RANK    16
#define SCALING 2.0f      // alpha/rank = 32/16

typedef __attribute__((ext_vector_type(8))) short          bf16x8;
typedef __attribute__((ext_vector_type(4))) float          f32x4;
typedef __attribute__((ext_vector_type(4))) float          fl4;
typedef __attribute__((ext_vector_type(4))) unsigned short u16x4;
typedef __attribute__((ext_vector_type(8))) unsigned short u16x8;

static __device__ __forceinline__ unsigned short f2bf(float f) {
  union { float f; uint32_t u; } v; v.f = f;
  return (unsigned short)((v.u + 0x7fffu + ((v.u >> 16) & 1u)) >> 16);  // RNE
}

static __device__ __forceinline__ void gload16(const void* g, void* l) {
  __builtin_amdgcn_global_load_lds(
      (const __attribute__((address_space(1))) uint32_t*)g,
      (__attribute__((address_space(3))) uint32_t*)l,
      16, 0, 0);
}

// ---------------------------------------------------------------------------
// W_eff[o][i] = bf16( W[o][i] + SCALING * sum_r B[o][r] * A[r][i] )
// ---------------------------------------------------------------------------
__global__ void merge_w_kernel(const float* __restrict__ W,
                               const float* __restrict__ lA,
                               const float* __restrict__ lB,
                               unsigned short* __restrict__ Weff) {
  __shared__ float Bs[RANK];
  const int o = blockIdx.x;
  if (threadIdx.x < RANK) Bs[threadIdx.x] = lB[o * RANK + threadIdx.x] * SCALING;
  __syncthreads();
  for (int c = threadIdx.x * 4; c < IN_F; c += 256 * 4) {
    fl4 w = *(const fl4*)(W + (size_t)o * IN_F + c);
#pragma unroll
    for (int r = 0; r < RANK; ++r) {
      const float b = Bs[r];
      const fl4 a = *(const fl4*)(lA + (size_t)r * IN_F + c);
      w[0] += b * a[0]; w[1] += b * a[1]; w[2] += b * a[2]; w[3] += b * a[3];
    }
    u16x4 p;
    p[0] = f2bf(w[0]); p[1] = f2bf(w[1]); p[2] = f2bf(w[2]); p[3] = f2bf(w[3]);
    *(u16x4*)(Weff + (size_t)o * IN_F + c) = p;
  }
}

// ---------------------------------------------------------------------------
__global__ void conv_x_kernel(const float* __restrict__ x,
                              unsigned short* __restrict__ xb) {
  const size_t i = ((size_t)blockIdx.x * 256 + threadIdx.x) * 8;
  const fl4 a = *(const fl4*)(x + i);
  const fl4 b = *(const fl4*)(x + i + 4);
  u16x8 p;
  p[0] = f2bf(a[0]); p[1] = f2bf(a[1]); p[2] = f2bf(a[2]); p[3] = f2bf(a[3]);
  p[4] = f2bf(b[0]); p[5] = f2bf(b[1]); p[6] = f2bf(b[2]); p[7] = f2bf(b[3]);
  *(u16x8*)(xb + i) = p;
}

// ---------------------------------------------------------------------------
// 256x256 tile, BK=64, 8 waves (2Mx4N), phase-split K-loop, counted vmcnt.
// LDS: A[2buf][2half][128][64] bf16 at 0, B same at 64KB. Halves row-major,
// bank-swizzle: stored colbyte = logical colbyte ^ ((row&7)<<4), realized as
// pre-swizzled GLOBAL source (linear gload_lds dest) + swizzled ds_read addr.
// ---------------------------------------------------------------------------
__global__ __launch_bounds__(512, 2) void gemm8p_kernel(
    const unsigned short* __restrict__ X,    // [8192][4096] bf16
    const unsigned short* __restrict__ Wf,   // [4096][4096] bf16
    float* __restrict__ Out) {
  __shared__ char lds[131072];
  const int tid  = threadIdx.x;
  const int lane = tid & 63;
  const int wave = tid >> 6;
  const int wr = wave >> 2;            // 0..1 (M)
  const int wc = wave & 3;             // 0..3 (N)
  const int fr = lane & 15;
  const int fq = lane >> 4;

  // XCD-aware bijective swizzle (512 % 8 == 0)
  const int bid = blockIdx.x;
  const int swz = (bid & 7) * 64 + (bid >> 3);
  const int tm = swz & 31;             // 32 M-tiles
  const int tn = swz >> 5;             // 16 N-tiles
  const int m0 = tm << 8;
  const int n0 = tn << 8;

  const unsigned short* Ag = X  + (size_t)m0 * IN_F;
  const unsigned short* Bg = Wf + (size_t)n0 * IN_F;

  // staging lane constants: window = 8 rows x 64 cols = 1024B, slot = 16B
  const int rIW = lane >> 3;                    // row within 8-row window
  const int csw = ((lane & 7) ^ rIW) << 3;      // pre-swizzled source col (elems)

  // ds_read address parts (bytes)
  const int aBase = wr * 16384 + fr * 128;                           // within A buf
  const int bBase = 65536 + (wc >> 1) * 16384 + (wc & 1) * 8192 + fr * 128;
  const int cA0 = (fq << 4) ^ ((fr & 7) << 4);                       // kk=0 colbyte
  const int cA1 = cA0 ^ 64;                                          // kk=1

#define STAGE(OP, H, BUF, K) do {                                              \
    const unsigned short* _g = (OP) ? Bg : Ag;                                 \
    const int _r0 = (H) * 128 + wave * 16 + rIW;                               \
    char* _d = lds + (OP) * 65536 + (BUF) * 32768 + (H) * 16384 +              \
               wave * 2048 + (lane << 4);                                      \
    gload16(_g + (size_t)_r0 * IN_F + (K) + csw, _d);                          \
    gload16(_g + (size_t)(_r0 + 8) * IN_F + (K) + csw, _d + 1024);             \
  } while (0)

#define LDA(BUF, M, KK) (*(const bf16x8*)(lds + (BUF) * 32768 + aBase + (M) * 2048 + (KK)))
#define LDB(BUF, N, KK) (*(const bf16x8*)(lds + (BUF) * 32768 + bBase + (N) * 2048 + (KK)))

  f32x4 acc[8][4];
#pragma unroll
  for (int i = 0; i < 8; ++i)
#pragma unroll
    for (int j = 0; j < 4; ++j) acc[i][j] = (f32x4){0.f, 0.f, 0.f, 0.f};

  bf16x8 a[8], b0[4], b1[4];

  // prologue: tile 0 -> buf 0 (8 issues/wave)
  STAGE(0, 0, 0, 0); STAGE(0, 1, 0, 0); STAGE(1, 0, 0, 0); STAGE(1, 1, 0, 0);

  for (int t = 0; t < 64; ++t) {
    const int b  = t & 1;
    const int nb = b ^ 1;
    const int kn = (t + 1) << 6;
    const bool pf = (t + 1 < 64);

    // ---- phase 0: (mh0,nh0). stage A-h0(t+1); counted wait; read a,b0 ----
    if (pf) {
      STAGE(0, 0, nb, kn);
      asm volatile("s_waitcnt vmcnt(2)" ::: "memory");   // tile-t fully landed
    } else {
      asm volatile("s_waitcnt vmcnt(0)" ::: "memory");
    }
    __builtin_amdgcn_s_barrier();
#pragma unroll
    for (int mi = 0; mi < 4; ++mi) { a[mi*2] = LDA(b, mi, cA0); a[mi*2+1] = LDA(b, mi, cA1); }
#pragma unroll
    for (int ni = 0; ni < 2; ++ni) { b0[ni*2] = LDB(b, ni, cA0); b0[ni*2+1] = LDB(b, ni, cA1); }
    asm volatile("s_waitcnt lgkmcnt(0)" ::: "memory");
    __builtin_amdgcn_s_setprio(1);
#pragma unroll
    for (int mi = 0; mi < 4; ++mi)
#pragma unroll
      for (int ni = 0; ni < 2; ++ni) {
        acc[mi][ni] = __builtin_amdgcn_mfma_f32_16x16x32_bf16(a[mi*2],   b0[ni*2],   acc[mi][ni], 0, 0, 0);
        acc[mi][ni] = __builtin_amdgcn_mfma_f32_16x16x32_bf16(a[mi*2+1], b0[ni*2+1], acc[mi][ni], 0, 0, 0);
      }
    __builtin_amdgcn_s_setprio(0);
    __builtin_amdgcn_s_barrier();

    // ---- phase 1: (mh0,nh1). stage A-h1(t+1); read b1; a reused ----
    if (pf) STAGE(0, 1, nb, kn);
    __builtin_amdgcn_s_barrier();
#pragma unroll
    for (int ni = 0; ni < 2; ++ni) { b1[ni*2] = LDB(b, 2+ni, cA0); b1[ni*2+1] = LDB(b, 2+ni, cA1); }
    asm volatile("s_waitcnt lgkmcnt(0)" ::: "memory");
    __builtin_amdgcn_s_setprio(1);
#pragma unroll
    for (int mi = 0; mi < 4; ++mi)
#pragma unroll
      for (int ni = 0; ni < 2; ++ni) {
        acc[mi][2+ni] = __builtin_amdgcn_mfma_f32_16x16x32_bf16(a[mi*2],   b1[ni*2],   acc[mi][2+ni], 0, 0, 0);
        acc[mi][2+ni] = __builtin_amdgcn_mfma_f32_16x16x32_bf16(a[mi*2+1], b1[ni*2+1], acc[mi][2+ni], 0, 0, 0);
      }
    __builtin_amdgcn_s_setprio(0);
    __builtin_amdgcn_s_barrier();

    // ---- phase 2: (mh1,nh1). stage B-h0(t+1); read a(mh1); b1 reused ----
    if (pf) STAGE(1, 0, nb, kn);
    __builtin_amdgcn_s_barrier();
#pragma unroll
    for (int mi = 0; mi < 4; ++mi) { a[mi*2] = LDA(b, 4+mi, cA0); a[mi*2+1] = LDA(b, 4+mi, cA1); }
    asm volatile("s_waitcnt lgkmcnt(0)" ::: "memory");
    __builtin_amdgcn_s_setprio(1);
#pragma unroll
    for (int mi = 0; mi < 4; ++mi)
#pragma unroll
      for (int ni = 0; ni < 2; ++ni) {
        acc[4+mi][2+ni] = __builtin_amdgcn_mfma_f32_16x16x32_bf16(a[mi*2],   b1[ni*2],   acc[4+mi][2+ni], 0, 0, 0);
        acc[4+mi][2+ni] = __builtin_amdgcn_mfma_f32_16x16x32_bf16(a[mi*2+1], b1[ni*2+1], acc[4+mi][2+ni], 0, 0, 0);
      }
    __builtin_amdgcn_s_setprio(0);
    __builtin_amdgcn_s_barrier();

    // ---- phase 3: (mh1,nh0). stage B-h1(t+1); read b0 again ----
    if (pf) STAGE(1, 1, nb, kn);
    __builtin_amdgcn_s_barrier();
#pragma unroll
    for (int ni = 0; ni < 2; ++ni) { b0[ni*2] = LDB(b, ni, cA0); b0[ni*2+1] = LDB(b, ni, cA1); }
    asm volatile("s_waitcnt lgkmcnt(0)" ::: "memory");
    __builtin_amdgcn_s_setprio(1);
#pragma unroll
    for (int mi = 0; mi < 4; ++mi)
#pragma unroll
      for (int ni = 0; ni < 2; ++ni) {
        acc[4+mi][ni] = __builtin_amdgcn_mfma_f32_16x16x32_bf16(a[mi*2],   b0[ni*2],   acc[4+mi][ni], 0, 0, 0);
        acc[4+mi][ni] = __builtin_amdgcn_mfma_f32_16x16x32_bf16(a[mi*2+1], b0[ni*2+1], acc[4+mi][ni], 0, 0, 0);
      }
    __builtin_amdgcn_s_setprio(0);
    __builtin_amdgcn_s_barrier();
  }

  // ---- epilogue: C[row = m*16+fq*4+j][col = n*16+fr] ----
#pragma unroll
  for (int mi = 0; mi < 8; ++mi) {
    const int row0 = m0 + wr * 128 + mi * 16 + fq * 4;
#pragma unroll
    for (int ni = 0; ni < 4; ++ni) {
      const int col = n0 + wc * 64 + ni * 16 + fr;
#pragma unroll
      for (int j = 0; j < 4; ++j)
        Out[(size_t)(row0 + j) * OUT_F + col] = acc[mi][ni][j];
    }
  }
#undef STAGE
#undef LDA
#undef LDB
}

// ---------------------------------------------------------------------------
// mid-ws fallback: 128^2 m97-structure GEMM reading f32 x directly
// ---------------------------------------------------------------------------
__global__ __launch_bounds__(256) void gemm_f32x_kernel(
    const float* __restrict__ X,
    const unsigned short* __restrict__ Weff,
    float* __restrict__ Out) {
  __shared__ unsigned short As[128][32];
  __shared__ unsigned short Bs[128][32];

  const int tid  = threadIdx.x;
  const int lane = tid & 63;
  const int wave = tid >> 6;
  const int wr = wave >> 1, wc = wave & 1;
  const int fr = lane & 15, fq = lane >> 4;

  const int bid = blockIdx.x;
  const int m0 = (bid & 63) * 128;
  const int n0 = (bid >> 6) * 128;

  f32x4 acc[4][4];
#pragma unroll
  for (int i = 0; i < 4; ++i)
#pragma unroll
    for (int j = 0; j < 4; ++j) acc[i][j] = (f32x4){0.f, 0.f, 0.f, 0.f};

  const int srow = tid >> 2;
  const int sseg = tid & 3;

  for (int k0 = 0; k0 < IN_F; k0 += 32) {
    if (k0) __syncthreads();
    {
      const unsigned short* gB = Weff + (size_t)(n0 + srow) * IN_F + k0 + sseg * 8;
      gload16(gB, &Bs[srow][sseg * 8]);
      gload16(gB + (size_t)64 * IN_F, &Bs[64 + srow][sseg * 8]);
    }
#pragma unroll
    for (int it = 0; it < 4; ++it) {
      const int c   = tid + it * 256;
      const int row = c >> 3;
      const int c4  = (c & 7) * 4;
      const fl4 v = *(const fl4*)(X + (size_t)(m0 + row) * IN_F + k0 + c4);
      u16x4 p;
      p[0] = f2bf(v[0]); p[1] = f2bf(v[1]); p[2] = f2bf(v[2]); p[3] = f2bf(v[3]);
      *(u16x4*)&As[row][c4] = p;
    }
    __syncthreads();

    bf16x8 af[4], bfm[4];
#pragma unroll
    for (int m = 0; m < 4; ++m)
      af[m] = *(const bf16x8*)&As[wr * 64 + m * 16 + fr][fq * 8];
#pragma unroll
    for (int n = 0; n < 4; ++n)
      bfm[n] = *(const bf16x8*)&Bs[wc * 64 + n * 16 + fr][fq * 8];
#pragma unroll
    for (int m = 0; m < 4; ++m)
#pragma unroll
      for (int n = 0; n < 4; ++n)
        acc[m][n] = __builtin_amdgcn_mfma_f32_16x16x32_bf16(af[m], bfm[n], acc[m][n], 0, 0, 0);
  }

#pragma unroll
  for (int m = 0; m < 4; ++m) {
    const int row0 = m0 + wr * 64 + m * 16 + fq * 4;
#pragma unroll
    for (int n = 0; n < 4; ++n) {
      const int col = n0 + wc * 64 + n * 16 + fr;
#pragma unroll
      for (int j = 0; j < 4; ++j)
        Out[(size_t)(row0 + j) * OUT_F + col] = acc[m][n][j];
    }
  }
}

// ---------------------------------------------------------------------------
// never-path fallbacks (tiny ws)
// ---------------------------------------------------------------------------
__global__ void lora_r_kernel(const float* __restrict__ x,
                              const float* __restrict__ lA,
                              float* __restrict__ r) {
  const int idx = blockIdx.x * 256 + threadIdx.x;
  const int m = idx / RANK, rr = idx % RANK;
  float acc = 0.f;
  for (int k = 0; k < IN_F; ++k)
    acc += x[(size_t)m * IN_F + k] * lA[(size_t)rr * IN_F + k];
  r[idx] = acc * SCALING;
}

__global__ void naive_out_kernel(const float* __restrict__ x,
                                 const float* __restrict__ W,
                                 const float* __restrict__ lB,
                                 const float* __restrict__ r,
                                 float* __restrict__ out) {
  const size_t idx = (size_t)blockIdx.x * 256 + threadIdx.x;
  const int m = (int)(idx / OUT_F), n = (int)(idx % OUT_F);
  float acc = 0.f;
  for (int k = 0; k < IN_F; ++k)
    acc += x[(size_t)m * IN_F + k] * W[(size_t)n * IN_F + k];
#pragma unroll
  for (int rr = 0; rr < RANK; ++rr)
    acc += r[(size_t)m * RANK + rr] * lB[(size_t)n * RANK + rr];
  out[idx] = acc;
}

// ---------------------------------------------------------------------------
extern "C" void kernel_launch(void* const* d_in, const int* in_sizes, int n_in,
                              void* d_out, int out_size, void* d_ws, size_t ws_size,
                              hipStream_t stream) {
  const float* x  = (const float*)d_in[0];
  const float* W  = (const float*)d_in[1];
  const float* lA = (const float*)d_in[2];
  const float* lB = (const float*)d_in[3];
  float* out = (float*)d_out;

  const size_t weff_bytes = (size_t)OUT_F * IN_F * 2;   // 32 MiB
  const size_t xb_bytes   = (size_t)MTOK * IN_F * 2;    // 64 MiB

  if (ws_size >= weff_bytes + xb_bytes) {
    unsigned short* Weff = (unsigned short*)d_ws;
    unsigned short* xb   = (unsigned short*)((char*)d_ws + weff_bytes);
    merge_w_kernel<<<OUT_F, 256, 0, stream>>>(W, lA, lB, Weff);
    conv_x_kernel<<<(MTOK * (size_t)IN_F) / (256 * 8), 256, 0, stream>>>(x, xb);
    gemm8p_kernel<<<(MTOK / 256) * (OUT_F / 256), 512, 0, stream>>>(xb, Weff, out);
  } else if (ws_size >= weff_bytes) {
    unsigned short* Weff = (unsigned short*)d_ws;
    merge_w_kernel<<<OUT_F, 256, 0, stream>>>(W, lA, lB, Weff);
    gemm_f32x_kernel<<<(MTOK / 128) * (OUT_F / 128), 256, 0, stream>>>(x, Weff, out);
  } else {
    float* r = (float*)d_ws;
    lora_r_kernel<<<(MTOK * RANK) / 256, 256, 0, stream>>>(x, lA, r);
    naive_out_kernel<<<(size_t)MTOK * OUT_F / 256, 256, 0, stream>>>(x, W, lB, r, out);
  }
}

// Round 3
// 340.923 us; speedup vs baseline: 1.2308x; 1.0676x over previous
//
#include <hip/hip_runtime.h>
#include <stdint.h>
#include <stddef.h>

#define IN_F    4096
#define OUT_F   4096
#define MTOK    8192      // 4 * 2048 tokens
#define RANK    16
#define SCALING 2.0f      // alpha/rank = 32/16

typedef __attribute__((ext_vector_type(8))) short          bf16x8;
typedef __attribute__((ext_vector_type(4))) float          f32x4;
typedef __attribute__((ext_vector_type(4))) float          fl4;
typedef __attribute__((ext_vector_type(4))) unsigned short u16x4;
typedef __attribute__((ext_vector_type(8))) unsigned short u16x8;

static __device__ __forceinline__ unsigned short f2bf(float f) {
  union { float f; uint32_t u; } v; v.f = f;
  return (unsigned short)((v.u + 0x7fffu + ((v.u >> 16) & 1u)) >> 16);  // RNE
}

static __device__ __forceinline__ void gload16(const void* g, void* l) {
  __builtin_amdgcn_global_load_lds(
      (const __attribute__((address_space(1))) uint32_t*)g,
      (__attribute__((address_space(3))) uint32_t*)l,
      16, 0, 0);
}

// ---------------------------------------------------------------------------
// W_eff[o][i] = bf16( W[o][i] + SCALING * sum_r B[o][r] * A[r][i] )
// ---------------------------------------------------------------------------
__global__ void merge_w_kernel(const float* __restrict__ W,
                               const float* __restrict__ lA,
                               const float* __restrict__ lB,
                               unsigned short* __restrict__ Weff) {
  __shared__ float Bs[RANK];
  const int o = blockIdx.x;
  if (threadIdx.x < RANK) Bs[threadIdx.x] = lB[o * RANK + threadIdx.x] * SCALING;
  __syncthreads();
  for (int c = threadIdx.x * 4; c < IN_F; c += 256 * 4) {
    fl4 w = *(const fl4*)(W + (size_t)o * IN_F + c);
#pragma unroll
    for (int r = 0; r < RANK; ++r) {
      const float b = Bs[r];
      const fl4 a = *(const fl4*)(lA + (size_t)r * IN_F + c);
      w[0] += b * a[0]; w[1] += b * a[1]; w[2] += b * a[2]; w[3] += b * a[3];
    }
    u16x4 p;
    p[0] = f2bf(w[0]); p[1] = f2bf(w[1]); p[2] = f2bf(w[2]); p[3] = f2bf(w[3]);
    *(u16x4*)(Weff + (size_t)o * IN_F + c) = p;
  }
}

// ---------------------------------------------------------------------------
__global__ void conv_x_kernel(const float* __restrict__ x,
                              unsigned short* __restrict__ xb) {
  const size_t i = ((size_t)blockIdx.x * 256 + threadIdx.x) * 8;
  const fl4 a = *(const fl4*)(x + i);
  const fl4 b = *(const fl4*)(x + i + 4);
  u16x8 p;
  p[0] = f2bf(a[0]); p[1] = f2bf(a[1]); p[2] = f2bf(a[2]); p[3] = f2bf(a[3]);
  p[4] = f2bf(b[0]); p[5] = f2bf(b[1]); p[6] = f2bf(b[2]); p[7] = f2bf(b[3]);
  *(u16x8*)(xb + i) = p;
}

// ---------------------------------------------------------------------------
// 256x256 tile, BK=64, 8 waves (2Mx4N), 4-phase K-loop, counted vmcnt.
// Stage chunks match per-wave temporal read order:
//   A-chunk c = abs rows {c*64..c*64+63} U {128+c*64..128+c*64+63}
//   B-chunk c = rows c*32..c*32+31 of each 64-row wave strip
// Stage order/tile: [Bc0, Bc1, Ac0, Ac1]; waits: ph0 vmcnt(4), ph1 vmcnt(4).
// Only ph0's 12 fragment reads are latency-exposed; the rest are issued
// post-MFMA in the previous phase.
// ---------------------------------------------------------------------------
__global__ __launch_bounds__(512, 2) void gemm8p_kernel(
    const unsigned short* __restrict__ X,    // [8192][4096] bf16
    const unsigned short* __restrict__ Wf,   // [4096][4096] bf16
    float* __restrict__ Out) {
  __shared__ char lds[131072];
  const int tid  = threadIdx.x;
  const int lane = tid & 63;
  const int wave = tid >> 6;
  const int wr = wave >> 2;            // 0..1 (M half)
  const int wc = wave & 3;             // 0..3 (N strip)
  const int fr = lane & 15;
  const int fq = lane >> 4;

  // XCD-aware bijective swizzle (512 % 8 == 0)
  const int bid = blockIdx.x;
  const int swz = (bid & 7) * 64 + (bid >> 3);
  const int tm = swz & 31;             // 32 M-tiles
  const int tn = swz >> 5;             // 16 N-tiles
  const int m0 = tm << 8;
  const int n0 = tn << 8;

  const unsigned short* Ag = X  + (size_t)m0 * IN_F;
  const unsigned short* Bg = Wf + (size_t)n0 * IN_F;

  // staging lane constants: window = 8 rows x 64 cols = 1024B, slot = 16B
  const int rIW = lane >> 3;                    // row within 8-row window
  const int csw = ((lane & 7) ^ rIW) << 3;      // pre-swizzled source col (elems)

  // ds_read address parts (bytes)
  const int aBase = wr * 16384 + fr * 128;
  const int bBase = 65536 + (wc >> 1) * 16384 + (wc & 1) * 8192 + fr * 128;
  const int cA0 = (fq << 4) ^ ((fr & 7) << 4);  // kk=0 swizzled colbyte
  const int cA1 = cA0 ^ 64;                     // kk=1

  // A chunk C: each wave stages 16 rows of its half-interleaved chunk
#define STAGE_A(C, BUF, K) do {                                                \
    const int _rh = (C) * 64 + (wave & 3) * 16;                                \
    const int _r0 = (wave >> 2) * 128 + _rh + rIW;                             \
    char* _d = lds + (BUF) * 32768 + (wave >> 2) * 16384 + _rh * 128 +         \
               (lane << 4);                                                    \
    gload16(Ag + (size_t)_r0 * IN_F + (K) + csw, _d);                          \
    gload16(Ag + (size_t)(_r0 + 8) * IN_F + (K) + csw, _d + 1024);             \
  } while (0)

  // B chunk C: strip = wave>>1; rows C*32 + (wave&1)*16 .. +15 of that strip
#define STAGE_B(C, BUF, K) do {                                                \
    const int _s  = wave >> 1;                                                 \
    const int _rh = (_s & 1) * 64 + (C) * 32 + (wave & 1) * 16;                \
    const int _r0 = (_s >> 1) * 128 + _rh + rIW;                               \
    char* _d = lds + 65536 + (BUF) * 32768 + (_s >> 1) * 16384 + _rh * 128 +   \
               (lane << 4);                                                    \
    gload16(Bg + (size_t)_r0 * IN_F + (K) + csw, _d);                          \
    gload16(Bg + (size_t)(_r0 + 8) * IN_F + (K) + csw, _d + 1024);             \
  } while (0)

#define LDA(BUF, M, KK) (*(const bf16x8*)(lds + (BUF) * 32768 + aBase + (M) * 2048 + (KK)))
#define LDB(BUF, N, KK) (*(const bf16x8*)(lds + (BUF) * 32768 + bBase + (N) * 2048 + (KK)))

  f32x4 acc[8][4];
#pragma unroll
  for (int i = 0; i < 8; ++i)
#pragma unroll
    for (int j = 0; j < 4; ++j) acc[i][j] = (f32x4){0.f, 0.f, 0.f, 0.f};

  bf16x8 a[8], b0[4], b1[4];

  // prologue: tile 0 -> buf 0, order [Bc0, Bc1, Ac0, Ac1]
  STAGE_B(0, 0, 0); STAGE_B(1, 0, 0); STAGE_A(0, 0, 0); STAGE_A(1, 0, 0);

  for (int t = 0; t < 64; ++t) {
    const int bu = t & 1;
    const int nb = bu ^ 1;
    const int kn = (t + 1) << 6;
    const bool pf = (t + 1 < 64);

    // ---- phase 0: Q(0,0) = a(h0) x b0 ----
    if (pf) {
      STAGE_B(0, nb, kn);
      asm volatile("s_waitcnt vmcnt(4)" ::: "memory");  // Bc0,Bc1,Ac0 of t landed
    } else {
      asm volatile("s_waitcnt vmcnt(2)" ::: "memory");
    }
    __builtin_amdgcn_s_barrier();
#pragma unroll
    for (int mi = 0; mi < 4; ++mi) { a[mi*2] = LDA(bu, mi, cA0); a[mi*2+1] = LDA(bu, mi, cA1); }
#pragma unroll
    for (int ni = 0; ni < 2; ++ni) { b0[ni*2] = LDB(bu, ni, cA0); b0[ni*2+1] = LDB(bu, ni, cA1); }
    __builtin_amdgcn_s_setprio(1);
#pragma unroll
    for (int mi = 0; mi < 4; ++mi)
#pragma unroll
      for (int ni = 0; ni < 2; ++ni) {
        acc[mi][ni] = __builtin_amdgcn_mfma_f32_16x16x32_bf16(a[mi*2],   b0[ni*2],   acc[mi][ni], 0, 0, 0);
        acc[mi][ni] = __builtin_amdgcn_mfma_f32_16x16x32_bf16(a[mi*2+1], b0[ni*2+1], acc[mi][ni], 0, 0, 0);
      }
    __builtin_amdgcn_s_setprio(0);
#pragma unroll
    for (int ni = 0; ni < 2; ++ni) { b1[ni*2] = LDB(bu, 2+ni, cA0); b1[ni*2+1] = LDB(bu, 2+ni, cA1); }
    __builtin_amdgcn_s_barrier();

    // ---- phase 1: Q(0,1) = a(h0) x b1 ----
    if (pf) {
      STAGE_B(1, nb, kn);
      asm volatile("s_waitcnt vmcnt(4)" ::: "memory");  // Ac1 of t landed
    } else {
      asm volatile("s_waitcnt vmcnt(0)" ::: "memory");
    }
    __builtin_amdgcn_s_barrier();
    __builtin_amdgcn_s_setprio(1);
#pragma unroll
    for (int mi = 0; mi < 4; ++mi)
#pragma unroll
      for (int ni = 0; ni < 2; ++ni) {
        acc[mi][2+ni] = __builtin_amdgcn_mfma_f32_16x16x32_bf16(a[mi*2],   b1[ni*2],   acc[mi][2+ni], 0, 0, 0);
        acc[mi][2+ni] = __builtin_amdgcn_mfma_f32_16x16x32_bf16(a[mi*2+1], b1[ni*2+1], acc[mi][2+ni], 0, 0, 0);
      }
    __builtin_amdgcn_s_setprio(0);
#pragma unroll
    for (int mi = 0; mi < 4; ++mi) { a[mi*2] = LDA(bu, 4+mi, cA0); a[mi*2+1] = LDA(bu, 4+mi, cA1); }
    __builtin_amdgcn_s_barrier();

    // ---- phase 2: Q(1,1) = a(h1) x b1 ----
    if (pf) STAGE_A(0, nb, kn);
    __builtin_amdgcn_s_barrier();
    __builtin_amdgcn_s_setprio(1);
#pragma unroll
    for (int mi = 0; mi < 4; ++mi)
#pragma unroll
      for (int ni = 0; ni < 2; ++ni) {
        acc[4+mi][2+ni] = __builtin_amdgcn_mfma_f32_16x16x32_bf16(a[mi*2],   b1[ni*2],   acc[4+mi][2+ni], 0, 0, 0);
        acc[4+mi][2+ni] = __builtin_amdgcn_mfma_f32_16x16x32_bf16(a[mi*2+1], b1[ni*2+1], acc[4+mi][2+ni], 0, 0, 0);
      }
    __builtin_amdgcn_s_setprio(0);
#pragma unroll
    for (int ni = 0; ni < 2; ++ni) { b0[ni*2] = LDB(bu, ni, cA0); b0[ni*2+1] = LDB(bu, ni, cA1); }
    __builtin_amdgcn_s_barrier();

    // ---- phase 3: Q(1,0) = a(h1) x b0 ----
    if (pf) STAGE_A(1, nb, kn);
    __builtin_amdgcn_s_barrier();
    __builtin_amdgcn_s_setprio(1);
#pragma unroll
    for (int mi = 0; mi < 4; ++mi)
#pragma unroll
      for (int ni = 0; ni < 2; ++ni) {
        acc[4+mi][ni] = __builtin_amdgcn_mfma_f32_16x16x32_bf16(a[mi*2],   b0[ni*2],   acc[4+mi][ni], 0, 0, 0);
        acc[4+mi][ni] = __builtin_amdgcn_mfma_f32_16x16x32_bf16(a[mi*2+1], b0[ni*2+1], acc[4+mi][ni], 0, 0, 0);
      }
    __builtin_amdgcn_s_setprio(0);
    __builtin_amdgcn_s_barrier();
  }

  // ---- epilogue: C[row = m*16+fq*4+j][col = n*16+fr] ----
#pragma unroll
  for (int mi = 0; mi < 8; ++mi) {
    const int row0 = m0 + wr * 128 + mi * 16 + fq * 4;
#pragma unroll
    for (int ni = 0; ni < 4; ++ni) {
      const int col = n0 + wc * 64 + ni * 16 + fr;
#pragma unroll
      for (int j = 0; j < 4; ++j)
        Out[(size_t)(row0 + j) * OUT_F + col] = acc[mi][ni][j];
    }
  }
#undef STAGE_A
#undef STAGE_B
#undef LDA
#undef LDB
}

// ---------------------------------------------------------------------------
// mid-ws fallback: 128^2 m97-structure GEMM reading f32 x directly
// ---------------------------------------------------------------------------
__global__ __launch_bounds__(256) void gemm_f32x_kernel(
    const float* __restrict__ X,
    const unsigned short* __restrict__ Weff,
    float* __restrict__ Out) {
  __shared__ unsigned short As[128][32];
  __shared__ unsigned short Bs[128][32];

  const int tid  = threadIdx.x;
  const int lane = tid & 63;
  const int wave = tid >> 6;
  const int wr = wave >> 1, wc = wave & 1;
  const int fr = lane & 15, fq = lane >> 4;

  const int bid = blockIdx.x;
  const int m0 = (bid & 63) * 128;
  const int n0 = (bid >> 6) * 128;

  f32x4 acc[4][4];
#pragma unroll
  for (int i = 0; i < 4; ++i)
#pragma unroll
    for (int j = 0; j < 4; ++j) acc[i][j] = (f32x4){0.f, 0.f, 0.f, 0.f};

  const int srow = tid >> 2;
  const int sseg = tid & 3;

  for (int k0 = 0; k0 < IN_F; k0 += 32) {
    if (k0) __syncthreads();
    {
      const unsigned short* gB = Weff + (size_t)(n0 + srow) * IN_F + k0 + sseg * 8;
      gload16(gB, &Bs[srow][sseg * 8]);
      gload16(gB + (size_t)64 * IN_F, &Bs[64 + srow][sseg * 8]);
    }
#pragma unroll
    for (int it = 0; it < 4; ++it) {
      const int c   = tid + it * 256;
      const int row = c >> 3;
      const int c4  = (c & 7) * 4;
      const fl4 v = *(const fl4*)(X + (size_t)(m0 + row) * IN_F + k0 + c4);
      u16x4 p;
      p[0] = f2bf(v[0]); p[1] = f2bf(v[1]); p[2] = f2bf(v[2]); p[3] = f2bf(v[3]);
      *(u16x4*)&As[row][c4] = p;
    }
    __syncthreads();

    bf16x8 af[4], bfm[4];
#pragma unroll
    for (int m = 0; m < 4; ++m)
      af[m] = *(const bf16x8*)&As[wr * 64 + m * 16 + fr][fq * 8];
#pragma unroll
    for (int n = 0; n < 4; ++n)
      bfm[n] = *(const bf16x8*)&Bs[wc * 64 + n * 16 + fr][fq * 8];
#pragma unroll
    for (int m = 0; m < 4; ++m)
#pragma unroll
      for (int n = 0; n < 4; ++n)
        acc[m][n] = __builtin_amdgcn_mfma_f32_16x16x32_bf16(af[m], bfm[n], acc[m][n], 0, 0, 0);
  }

#pragma unroll
  for (int m = 0; m < 4; ++m) {
    const int row0 = m0 + wr * 64 + m * 16 + fq * 4;
#pragma unroll
    for (int n = 0; n < 4; ++n) {
      const int col = n0 + wc * 64 + n * 16 + fr;
#pragma unroll
      for (int j = 0; j < 4; ++j)
        Out[(size_t)(row0 + j) * OUT_F + col] = acc[m][n][j];
    }
  }
}

// ---------------------------------------------------------------------------
// never-path fallbacks (tiny ws)
// ---------------------------------------------------------------------------
__global__ void lora_r_kernel(const float* __restrict__ x,
                              const float* __restrict__ lA,
                              float* __restrict__ r) {
  const int idx = blockIdx.x * 256 + threadIdx.x;
  const int m = idx / RANK, rr = idx % RANK;
  float acc = 0.f;
  for (int k = 0; k < IN_F; ++k)
    acc += x[(size_t)m * IN_F + k] * lA[(size_t)rr * IN_F + k];
  r[idx] = acc * SCALING;
}

__global__ void naive_out_kernel(const float* __restrict__ x,
                                 const float* __restrict__ W,
                                 const float* __restrict__ lB,
                                 const float* __restrict__ r,
                                 float* __restrict__ out) {
  const size_t idx = (size_t)blockIdx.x * 256 + threadIdx.x;
  const int m = (int)(idx / OUT_F), n = (int)(idx % OUT_F);
  float acc = 0.f;
  for (int k = 0; k < IN_F; ++k)
    acc += x[(size_t)m * IN_F + k] * W[(size_t)n * IN_F + k];
#pragma unroll
  for (int rr = 0; rr < RANK; ++rr)
    acc += r[(size_t)m * RANK + rr] * lB[(size_t)n * RANK + rr];
  out[idx] = acc;
}

// ---------------------------------------------------------------------------
extern "C" void kernel_launch(void* const* d_in, const int* in_sizes, int n_in,
                              void* d_out, int out_size, void* d_ws, size_t ws_size,
                              hipStream_t stream) {
  const float* x  = (const float*)d_in[0];
  const float* W  = (const float*)d_in[1];
  const float* lA = (const float*)d_in[2];
  const float* lB = (const float*)d_in[3];
  float* out = (float*)d_out;

  const size_t weff_bytes = (size_t)OUT_F * IN_F * 2;   // 32 MiB
  const size_t xb_bytes   = (size_t)MTOK * IN_F * 2;    // 64 MiB

  if (ws_size >= weff_bytes + xb_bytes) {
    unsigned short* Weff = (unsigned short*)d_ws;
    unsigned short* xb   = (unsigned short*)((char*)d_ws + weff_bytes);
    merge_w_kernel<<<OUT_F, 256, 0, stream>>>(W, lA, lB, Weff);
    conv_x_kernel<<<(MTOK * (size_t)IN_F) / (256 * 8), 256, 0, stream>>>(x, xb);
    gemm8p_kernel<<<(MTOK / 256) * (OUT_F / 256), 512, 0, stream>>>(xb, Weff, out);
  } else if (ws_size >= weff_bytes) {
    unsigned short* Weff = (unsigned short*)d_ws;
    merge_w_kernel<<<OUT_F, 256, 0, stream>>>(W, lA, lB, Weff);
    gemm_f32x_kernel<<<(MTOK / 128) * (OUT_F / 128), 256, 0, stream>>>(x, Weff, out);
  } else {
    float* r = (float*)d_ws;
    lora_r_kernel<<<(MTOK * RANK) / 256, 256, 0, stream>>>(x, lA, r);
    naive_out_kernel<<<(size_t)MTOK * OUT_F / 256, 256, 0, stream>>>(x, W, lB, r, out);
  }
}